// Round 4
// baseline (368.102 us; speedup 1.0000x reference)
//
#include <hip/hip_runtime.h>
#include <hip/hip_bf16.h>

// GAT layer: xt = x@W; alpha = segment_softmax(leakyrelu(asrc[src]+adst[dst]));
// out = relu(mean_h(segment_sum(alpha*xt[src])) + bias)
// N=50000, F_IN=116, H=8, C=32, E=800000 (+N self loops)
//
// v4: aggregate = one WAVE per node (4 nodes/block), no LDS, no barriers.
//     Lane l holds channels [4l,4l+4) -> one dwordx4 per edge fetches the whole
//     1KB xt row per wave. Weights: 8-edge chunks, lane computes exp for
//     (edge l>>3, head l&7), distributed via 2 shuffles/edge. Head-mean via
//     shfl_xor(8/16/32). Scan writes offs twice (offs + cur) so scatter is
//     a single atomic + store.

#define F_IN 116
#define HC 256     // H*C
#define NHEAD 8
#define CDIM 32

// ---------------- zero cnt ----------------
__global__ void zero_k(int* __restrict__ p, int n) {
    int i = blockIdx.x * 256 + threadIdx.x;
    if (i < n) p[i] = 0;
}

// ---------------- GEMM: xt[N,256] = x[N,116] @ W[116,256] ----------------
__global__ __launch_bounds__(256) void gemm_xt(const float* __restrict__ x,
                                               const float* __restrict__ W,
                                               float* __restrict__ xt, int N) {
    __shared__ float xs[64 * F_IN];           // 29696 B
    const int t = threadIdx.x;
    const int row0 = blockIdx.x * 64;
    const int nrows = (N - row0 < 64) ? (N - row0) : 64;
    const int tot = nrows * F_IN;
    for (int i = t; i < tot; i += 256) xs[i] = x[(size_t)row0 * F_IN + i];
    __syncthreads();

    const int w = t >> 6;
    const int lane = t & 63;
    const int r0 = w * 16;

    float acc[16][4];
#pragma unroll
    for (int r = 0; r < 16; ++r)
#pragma unroll
        for (int j = 0; j < 4; ++j) acc[r][j] = 0.f;

    for (int k4 = 0; k4 < F_IN / 4; ++k4) {
        const int k = k4 * 4;
        float w0[4], w1[4], w2[4], w3[4];
#pragma unroll
        for (int j = 0; j < 4; ++j) {
            const float* Wk = W + k * HC + lane + 64 * j;
            w0[j] = Wk[0];
            w1[j] = Wk[HC];
            w2[j] = Wk[2 * HC];
            w3[j] = Wk[3 * HC];
        }
#pragma unroll
        for (int r = 0; r < 16; ++r) {
            float4 xv = *(const float4*)&xs[(r0 + r) * F_IN + k];
#pragma unroll
            for (int j = 0; j < 4; ++j)
                acc[r][j] = fmaf(xv.x, w0[j],
                            fmaf(xv.y, w1[j],
                            fmaf(xv.z, w2[j],
                            fmaf(xv.w, w3[j], acc[r][j]))));
        }
    }

#pragma unroll
    for (int r = 0; r < 16; ++r) {
        const int row = row0 + r0 + r;
        if (row < N) {
#pragma unroll
            for (int j = 0; j < 4; ++j)
                xt[(size_t)row * HC + lane + 64 * j] = acc[r][j];
        }
    }
}

// ---------------- alphas ----------------
__global__ void alphas_k(const float* __restrict__ xt,
                         const float* __restrict__ att_s,
                         const float* __restrict__ att_d,
                         float* __restrict__ asrc, float* __restrict__ adst, int NH) {
    int idx = blockIdx.x * 256 + threadIdx.x;    // n*8 + h
    if (idx >= NH) return;
    int h = idx & 7;
    int n = idx >> 3;
    const float4* xp = (const float4*)(xt + (size_t)n * HC + h * CDIM);
    const float4* sp = (const float4*)(att_s + h * CDIM);
    const float4* dp = (const float4*)(att_d + h * CDIM);
    float a = 0.f, b = 0.f;
#pragma unroll
    for (int q = 0; q < CDIM / 4; ++q) {
        float4 v = xp[q], sv = sp[q], dv = dp[q];
        a += v.x * sv.x + v.y * sv.y + v.z * sv.z + v.w * sv.w;
        b += v.x * dv.x + v.y * dv.y + v.z * dv.z + v.w * dv.w;
    }
    asrc[idx] = a;
    adst[idx] = b;
}

// ---------------- in-degree histogram ----------------
__global__ void hist_k(const int* __restrict__ dst, int* __restrict__ cnt, int E) {
    int e = blockIdx.x * 256 + threadIdx.x;
    if (e < E) atomicAdd(&cnt[dst[e]], 1);
}

// ---------------- parallel scan: 1024 elems/block; writes offs AND cur ----------------
__global__ __launch_bounds__(256) void scan1_k(const int* __restrict__ cnt,
                                               int* __restrict__ offs,
                                               int* __restrict__ cur,
                                               int* __restrict__ bsum, int N) {
    __shared__ int ts[256];
    const int t = threadIdx.x;
    const int base = blockIdx.x * 1024 + t * 4;
    int v[4];
    int s = 0;
#pragma unroll
    for (int j = 0; j < 4; ++j) {
        v[j] = (base + j < N) ? cnt[base + j] : 0;
        s += v[j];
    }
    ts[t] = s;
    __syncthreads();
    for (int off = 1; off < 256; off <<= 1) {
        int u = (t >= off) ? ts[t - off] : 0;
        __syncthreads();
        ts[t] += u;
        __syncthreads();
    }
    int run = t ? ts[t - 1] : 0;
#pragma unroll
    for (int j = 0; j < 4; ++j) {
        if (base + j < N) { offs[base + j] = run; cur[base + j] = run; }
        run += v[j];
    }
    if (t == 255) bsum[blockIdx.x] = ts[255];
}

__global__ void scan2_k(int* __restrict__ bsum, int* __restrict__ offs, int nb, int N) {
    if (threadIdx.x == 0 && blockIdx.x == 0) {
        int run = 0;
        for (int b = 0; b < nb; ++b) {
            int v = bsum[b];
            bsum[b] = run;
            run += v;
        }
        offs[N] = run;
    }
}

__global__ void scan3_k(int* __restrict__ offs, int* __restrict__ cur,
                        const int* __restrict__ bsum, int N) {
    int i = blockIdx.x * 256 + threadIdx.x;
    if (i < N) {
        int b = bsum[i >> 10];
        offs[i] += b;
        cur[i] += b;
    }
}

// ---------------- CSR scatter (cur pre-seeded with offsets) ----------------
__global__ void scatter_k(const int* __restrict__ src, const int* __restrict__ dst,
                          int* __restrict__ cur, int* __restrict__ csr, int E) {
    int e = blockIdx.x * 256 + threadIdx.x;
    if (e >= E) return;
    int p = atomicAdd(&cur[dst[e]], 1);
    csr[p] = src[e];
}

// ---------------- aggregate: one WAVE per destination node ----------------
// Lane l: fma-head h_f = l>>3, channels [4l, 4l+4). Weight-compute mapping:
// edge (chunk-local) l>>3, head l&7.
__global__ __launch_bounds__(256) void aggregate_k(const float* __restrict__ xt,
                                                   const float* __restrict__ asrc,
                                                   const float* __restrict__ adst,
                                                   const int* __restrict__ offs,
                                                   const int* __restrict__ csr,
                                                   const float* __restrict__ bias,
                                                   float* __restrict__ out, int N) {
    const int t = threadIdx.x;
    const int l = t & 63;
    const int n = blockIdx.x * 4 + (t >> 6);
    if (n >= N) return;

    const int h_f = l >> 3;          // head for fma/accumulation
    const int h_w = l & 7;           // head for weight compute
    const int e_w = l >> 3;          // chunk-local edge for weight compute

    const int beg = offs[n];
    const int d = offs[n + 1] - beg;

    const float adst_hw = adst[n * NHEAD + h_w];

    // self-loop
    float zs = asrc[n * NHEAD + h_f] + adst[n * NHEAD + h_f];
    zs = (zs > 0.f) ? zs : 0.2f * zs;
    const float wself = __expf(zs);
    float4 xv = *(const float4*)&xt[(size_t)n * HC + 4 * l];
    float a0 = wself * xv.x, a1 = wself * xv.y, a2 = wself * xv.z, a3 = wself * xv.w;
    float wsum = wself;

    for (int ch = 0; ch < d; ch += 8) {
        const int m = (d - ch < 8) ? (d - ch) : 8;
        // weight compute: lane handles edge e_w, head h_w
        int s_w = (e_w < m) ? csr[beg + ch + e_w] : n;
        float z = asrc[s_w * NHEAD + h_w] + adst_hw;
        z = (z > 0.f) ? z : 0.2f * z;
        float w_reg = __expf(z);
        for (int e = 0; e < m; ++e) {
            int s = __shfl(s_w, e << 3, 64);
            float w = __shfl(w_reg, (e << 3) + h_f, 64);
            float4 v = *(const float4*)&xt[(size_t)s * HC + 4 * l];
            a0 = fmaf(w, v.x, a0);
            a1 = fmaf(w, v.y, a1);
            a2 = fmaf(w, v.z, a2);
            a3 = fmaf(w, v.w, a3);
            wsum += w;
        }
    }

    const float inv = 1.f / (wsum + 1e-16f);
    a0 *= inv; a1 *= inv; a2 *= inv; a3 *= inv;

    // reduce over heads: lanes with equal (l&7) hold same channel group
#pragma unroll
    for (int o = 8; o <= 32; o <<= 1) {
        a0 += __shfl_xor(a0, o, 64);
        a1 += __shfl_xor(a1, o, 64);
        a2 += __shfl_xor(a2, o, 64);
        a3 += __shfl_xor(a3, o, 64);
    }

    if (l < 8) {
        const float* bp = bias + 4 * l;
        float4 r;
        r.x = fmaxf(a0 * 0.125f + bp[0], 0.f);
        r.y = fmaxf(a1 * 0.125f + bp[1], 0.f);
        r.z = fmaxf(a2 * 0.125f + bp[2], 0.f);
        r.w = fmaxf(a3 * 0.125f + bp[3], 0.f);
        *(float4*)&out[(size_t)n * CDIM + 4 * l] = r;
    }
}

extern "C" void kernel_launch(void* const* d_in, const int* in_sizes, int n_in,
                              void* d_out, int out_size, void* d_ws, size_t ws_size,
                              hipStream_t stream) {
    const float* x     = (const float*)d_in[0];
    const int*   ei    = (const int*)d_in[1];      // [2,E] int32: row0=src, row1=dst
    const float* W     = (const float*)d_in[2];
    const float* att_s = (const float*)d_in[3];
    const float* att_d = (const float*)d_in[4];
    const float* bias  = (const float*)d_in[5];
    float* out = (float*)d_out;

    const int N = in_sizes[0] / F_IN;    // 50000
    const int E = in_sizes[1] / 2;       // 800000

    // workspace layout
    float* xt   = (float*)d_ws;                        // 256N
    float* asrc = xt + (size_t)N * HC;                 // 8N
    float* adst = asrc + (size_t)N * NHEAD;            // 8N
    int*   offs = (int*)(adst + (size_t)N * NHEAD);    // N+4
    int*   bsum = offs + (N + 4);                      // 64
    int*   cnt  = bsum + 64;                           // N
    int*   cur  = cnt + N;                             // N
    int*   csr  = cur + N;                             // E

    const int nb = (N + 1023) / 1024;

    zero_k<<<(N + 255) / 256, 256, 0, stream>>>(cnt, N);
    gemm_xt<<<(N + 63) / 64, 256, 0, stream>>>(x, W, xt, N);
    alphas_k<<<(N * NHEAD + 255) / 256, 256, 0, stream>>>(xt, att_s, att_d, asrc, adst, N * NHEAD);
    hist_k<<<(E + 255) / 256, 256, 0, stream>>>(ei + E, cnt, E);
    scan1_k<<<nb, 256, 0, stream>>>(cnt, offs, cur, bsum, N);
    scan2_k<<<1, 64, 0, stream>>>(bsum, offs, nb, N);
    scan3_k<<<(N + 255) / 256, 256, 0, stream>>>(offs, cur, bsum, N);
    scatter_k<<<(E + 255) / 256, 256, 0, stream>>>(ei, ei + E, cur, csr, E);
    aggregate_k<<<(N + 3) / 4, 256, 0, stream>>>(xt, asrc, adst, offs, csr, bias, out, N);
}

// Round 5
// 322.575 us; speedup vs baseline: 1.1411x; 1.1411x over previous
//
#include <hip/hip_runtime.h>
#include <hip/hip_bf16.h>

// GAT layer: xt = x@W; alpha = segment_softmax(leakyrelu(asrc[src]+adst[dst]));
// out = relu(mean_h(segment_sum(alpha*xt[src])) + bias)
// N=50000, F_IN=116, H=8, C=32, E=800000 (+N self loops)
//
// v5: aggregate was BYTE-bound (v3->v4: VMEM insts 4x down, VALU 42->20%, dur
//     unchanged at 127us, 441MB @ 3.6TB/s effective). So: xt stored as bf16
//     (halves gather volume), alphas fused into the GEMM epilogue via half-wave
//     shfl_xor butterflies (f32 logits preserved; alphas_k kernel + 51MB read
//     eliminated). Aggregate unpacks bf16 with exact <<16 shifts.

#define F_IN 116
#define HC 256     // H*C
#define NHEAD 8
#define CDIM 32

typedef unsigned int uint32;
typedef unsigned short ushort16;

__device__ __forceinline__ unsigned short f2bf(float f) {
    uint32 u = __float_as_uint(f);
    u = (u + 0x7FFF + ((u >> 16) & 1)) >> 16;   // round-nearest-even
    return (unsigned short)u;
}

// ---------------- zero cnt ----------------
__global__ void zero_k(int* __restrict__ p, int n) {
    int i = blockIdx.x * 256 + threadIdx.x;
    if (i < n) p[i] = 0;
}

// ------- GEMM + fused alphas: xth[N,256](bf16), asrc/adst[N,8](f32) -------
__global__ __launch_bounds__(256) void gemm_xt(const float* __restrict__ x,
                                               const float* __restrict__ W,
                                               const float* __restrict__ att_s,
                                               const float* __restrict__ att_d,
                                               unsigned short* __restrict__ xth,
                                               float* __restrict__ asrc,
                                               float* __restrict__ adst, int N) {
    __shared__ float xs[64 * F_IN];           // 29696 B
    const int t = threadIdx.x;
    const int row0 = blockIdx.x * 64;
    const int nrows = (N - row0 < 64) ? (N - row0) : 64;
    const int tot = nrows * F_IN;
    for (int i = t; i < tot; i += 256) xs[i] = x[(size_t)row0 * F_IN + i];
    __syncthreads();

    const int w = t >> 6;
    const int lane = t & 63;
    const int r0 = w * 16;

    float acc[16][4];
#pragma unroll
    for (int r = 0; r < 16; ++r)
#pragma unroll
        for (int j = 0; j < 4; ++j) acc[r][j] = 0.f;

    for (int k4 = 0; k4 < F_IN / 4; ++k4) {
        const int k = k4 * 4;
        float w0[4], w1[4], w2[4], w3[4];
#pragma unroll
        for (int j = 0; j < 4; ++j) {
            const float* Wk = W + k * HC + lane + 64 * j;
            w0[j] = Wk[0];
            w1[j] = Wk[HC];
            w2[j] = Wk[2 * HC];
            w3[j] = Wk[3 * HC];
        }
#pragma unroll
        for (int r = 0; r < 16; ++r) {
            float4 xv = *(const float4*)&xs[(r0 + r) * F_IN + k];
#pragma unroll
            for (int j = 0; j < 4; ++j)
                acc[r][j] = fmaf(xv.x, w0[j],
                            fmaf(xv.y, w1[j],
                            fmaf(xv.z, w2[j],
                            fmaf(xv.w, w3[j], acc[r][j]))));
        }
    }

    // att vectors for this thread's 4 columns (col = lane + 64j, head = col>>5)
    float as_[4], ad_[4];
#pragma unroll
    for (int j = 0; j < 4; ++j) {
        as_[j] = att_s[lane + 64 * j];
        ad_[j] = att_d[lane + 64 * j];
    }
    const int hb = lane >> 5;   // half-wave id: heads 2j+hb

#pragma unroll
    for (int r = 0; r < 16; ++r) {
        const int row = row0 + r0 + r;
        // bf16 store of the row (coalesced 2B x 64 lanes per j)
        if (row < N) {
#pragma unroll
            for (int j = 0; j < 4; ++j)
                xth[(size_t)row * HC + lane + 64 * j] = f2bf(acc[r][j]);
        }
        // per-head alpha dots: butterfly within each 32-lane half
        float ps[4], pd[4];
#pragma unroll
        for (int j = 0; j < 4; ++j) {
            ps[j] = acc[r][j] * as_[j];
            pd[j] = acc[r][j] * ad_[j];
        }
#pragma unroll
        for (int o = 1; o <= 16; o <<= 1) {
#pragma unroll
            for (int j = 0; j < 4; ++j) {
                ps[j] += __shfl_xor(ps[j], o, 64);
                pd[j] += __shfl_xor(pd[j], o, 64);
            }
        }
        if (row < N && (lane == 0 || lane == 32)) {
#pragma unroll
            for (int j = 0; j < 4; ++j) {
                asrc[row * NHEAD + 2 * j + hb] = ps[j];
                adst[row * NHEAD + 2 * j + hb] = pd[j];
            }
        }
    }
}

// ---------------- in-degree histogram ----------------
__global__ void hist_k(const int* __restrict__ dst, int* __restrict__ cnt, int E) {
    int e = blockIdx.x * 256 + threadIdx.x;
    if (e < E) atomicAdd(&cnt[dst[e]], 1);
}

// ---------------- parallel scan: 1024 elems/block; writes offs AND cur ----------------
__global__ __launch_bounds__(256) void scan1_k(const int* __restrict__ cnt,
                                               int* __restrict__ offs,
                                               int* __restrict__ cur,
                                               int* __restrict__ bsum, int N) {
    __shared__ int ts[256];
    const int t = threadIdx.x;
    const int base = blockIdx.x * 1024 + t * 4;
    int v[4];
    int s = 0;
#pragma unroll
    for (int j = 0; j < 4; ++j) {
        v[j] = (base + j < N) ? cnt[base + j] : 0;
        s += v[j];
    }
    ts[t] = s;
    __syncthreads();
    for (int off = 1; off < 256; off <<= 1) {
        int u = (t >= off) ? ts[t - off] : 0;
        __syncthreads();
        ts[t] += u;
        __syncthreads();
    }
    int run = t ? ts[t - 1] : 0;
#pragma unroll
    for (int j = 0; j < 4; ++j) {
        if (base + j < N) { offs[base + j] = run; cur[base + j] = run; }
        run += v[j];
    }
    if (t == 255) bsum[blockIdx.x] = ts[255];
}

__global__ void scan2_k(int* __restrict__ bsum, int* __restrict__ offs, int nb, int N) {
    if (threadIdx.x == 0 && blockIdx.x == 0) {
        int run = 0;
        for (int b = 0; b < nb; ++b) {
            int v = bsum[b];
            bsum[b] = run;
            run += v;
        }
        offs[N] = run;
    }
}

__global__ void scan3_k(int* __restrict__ offs, int* __restrict__ cur,
                        const int* __restrict__ bsum, int N) {
    int i = blockIdx.x * 256 + threadIdx.x;
    if (i < N) {
        int b = bsum[i >> 10];
        offs[i] += b;
        cur[i] += b;
    }
}

// ---------------- CSR scatter (cur pre-seeded with offsets) ----------------
__global__ void scatter_k(const int* __restrict__ src, const int* __restrict__ dst,
                          int* __restrict__ cur, int* __restrict__ csr, int E) {
    int e = blockIdx.x * 256 + threadIdx.x;
    if (e >= E) return;
    int p = atomicAdd(&cur[dst[e]], 1);
    csr[p] = src[e];
}

// ---------------- aggregate: one WAVE per destination node ----------------
// Lane l: fma-head h_f = l>>3, channels [4l, 4l+4). Weight-compute mapping:
// edge (chunk-local) l>>3, head l&7.
__global__ __launch_bounds__(256) void aggregate_k(const unsigned short* __restrict__ xth,
                                                   const float* __restrict__ asrc,
                                                   const float* __restrict__ adst,
                                                   const int* __restrict__ offs,
                                                   const int* __restrict__ csr,
                                                   const float* __restrict__ bias,
                                                   float* __restrict__ out, int N) {
    const int t = threadIdx.x;
    const int l = t & 63;
    const int n = blockIdx.x * 4 + (t >> 6);
    if (n >= N) return;

    const int h_f = l >> 3;          // head for fma/accumulation
    const int h_w = l & 7;           // head for weight compute
    const int e_w = l >> 3;          // chunk-local edge for weight compute

    const int beg = offs[n];
    const int d = offs[n + 1] - beg;

    const float adst_hw = adst[n * NHEAD + h_w];

    // self-loop
    float zs = asrc[n * NHEAD + h_f] + adst[n * NHEAD + h_f];
    zs = (zs > 0.f) ? zs : 0.2f * zs;
    const float wself = __expf(zs);

    uint2 sv = ((const uint2*)(xth + (size_t)n * HC))[l];
    float f0 = __uint_as_float(sv.x << 16);
    float f1 = __uint_as_float(sv.x & 0xFFFF0000u);
    float f2 = __uint_as_float(sv.y << 16);
    float f3 = __uint_as_float(sv.y & 0xFFFF0000u);
    float a0 = wself * f0, a1 = wself * f1, a2 = wself * f2, a3 = wself * f3;
    float wsum = wself;

    for (int ch = 0; ch < d; ch += 8) {
        const int m = (d - ch < 8) ? (d - ch) : 8;
        // weight compute: lane handles edge e_w, head h_w
        int s_w = (e_w < m) ? csr[beg + ch + e_w] : n;
        float z = asrc[s_w * NHEAD + h_w] + adst_hw;
        z = (z > 0.f) ? z : 0.2f * z;
        float w_reg = __expf(z);
        for (int e = 0; e < m; ++e) {
            int s = __shfl(s_w, e << 3, 64);
            float w = __shfl(w_reg, (e << 3) + h_f, 64);
            uint2 v = ((const uint2*)(xth + (size_t)s * HC))[l];
            float v0 = __uint_as_float(v.x << 16);
            float v1 = __uint_as_float(v.x & 0xFFFF0000u);
            float v2 = __uint_as_float(v.y << 16);
            float v3 = __uint_as_float(v.y & 0xFFFF0000u);
            a0 = fmaf(w, v0, a0);
            a1 = fmaf(w, v1, a1);
            a2 = fmaf(w, v2, a2);
            a3 = fmaf(w, v3, a3);
            wsum += w;
        }
    }

    const float inv = 1.f / (wsum + 1e-16f);
    a0 *= inv; a1 *= inv; a2 *= inv; a3 *= inv;

    // reduce over heads: lanes with equal (l&7) hold same channel group
#pragma unroll
    for (int o = 8; o <= 32; o <<= 1) {
        a0 += __shfl_xor(a0, o, 64);
        a1 += __shfl_xor(a1, o, 64);
        a2 += __shfl_xor(a2, o, 64);
        a3 += __shfl_xor(a3, o, 64);
    }

    if (l < 8) {
        const float* bp = bias + 4 * l;
        float4 r;
        r.x = fmaxf(a0 * 0.125f + bp[0], 0.f);
        r.y = fmaxf(a1 * 0.125f + bp[1], 0.f);
        r.z = fmaxf(a2 * 0.125f + bp[2], 0.f);
        r.w = fmaxf(a3 * 0.125f + bp[3], 0.f);
        *(float4*)&out[(size_t)n * CDIM + 4 * l] = r;
    }
}

extern "C" void kernel_launch(void* const* d_in, const int* in_sizes, int n_in,
                              void* d_out, int out_size, void* d_ws, size_t ws_size,
                              hipStream_t stream) {
    const float* x     = (const float*)d_in[0];
    const int*   ei    = (const int*)d_in[1];      // [2,E] int32: row0=src, row1=dst
    const float* W     = (const float*)d_in[2];
    const float* att_s = (const float*)d_in[3];
    const float* att_d = (const float*)d_in[4];
    const float* bias  = (const float*)d_in[5];
    float* out = (float*)d_out;

    const int N = in_sizes[0] / F_IN;    // 50000
    const int E = in_sizes[1] / 2;       // 800000

    // workspace layout (16B-aligned slices; N%4==0)
    unsigned short* xth = (unsigned short*)d_ws;          // 256N bf16 (2B)
    float* asrc = (float*)(xth + (size_t)N * HC);         // 8N f32
    float* adst = asrc + (size_t)N * NHEAD;               // 8N
    int*   offs = (int*)(adst + (size_t)N * NHEAD);       // N+4
    int*   bsum = offs + (N + 4);                         // 64
    int*   cnt  = bsum + 64;                              // N
    int*   cur  = cnt + N;                                // N
    int*   csr  = cur + N;                                // E

    const int nb = (N + 1023) / 1024;

    zero_k<<<(N + 255) / 256, 256, 0, stream>>>(cnt, N);
    gemm_xt<<<(N + 63) / 64, 256, 0, stream>>>(x, W, att_s, att_d, xth, asrc, adst, N);
    hist_k<<<(E + 255) / 256, 256, 0, stream>>>(ei + E, cnt, E);
    scan1_k<<<nb, 256, 0, stream>>>(cnt, offs, cur, bsum, N);
    scan2_k<<<1, 64, 0, stream>>>(bsum, offs, nb, N);
    scan3_k<<<(N + 255) / 256, 256, 0, stream>>>(offs, cur, bsum, N);
    scatter_k<<<(E + 255) / 256, 256, 0, stream>>>(ei, ei + E, cur, csr, E);
    aggregate_k<<<(N + 3) / 4, 256, 0, stream>>>(xth, asrc, adst, offs, csr, bias, out, N);
}

// Round 6
// 278.948 us; speedup vs baseline: 1.3196x; 1.1564x over previous
//
#include <hip/hip_runtime.h>
#include <hip/hip_bf16.h>

// GAT layer: xt = x@W; alpha = segment_softmax(leakyrelu(asrc[src]+adst[dst]));
// out = relu(mean_h(segment_sum(alpha*xt[src])) + bias)
// N=50000, F_IN=116, H=8, C=32, E=800000 (+N self loops)
//
// v6: alphas via precomputed wsh = W@[att_s|att_d] (116x16) then x@wsh —
//     kills v5's 640-shuffle GEMM epilogue (85us -> pure GEMM) and stays f32
//     exact. GEMM moves to 512-thread blocks (24 waves/CU vs 12; grid was the
//     occupancy cap). Hist captures per-edge bucket rank from the atomic
//     return -> scatter has no atomic; scan3/cur eliminated (bsum-add folded
//     into scatter/aggregate). Aggregate: unrolled 8-edge fast path.

#define F_IN 116
#define HC 256     // H*C
#define NHEAD 8
#define CDIM 32

typedef unsigned int uint32;

__device__ __forceinline__ unsigned short f2bf(float f) {
    uint32 u = __float_as_uint(f);
    u = (u + 0x7FFF + ((u >> 16) & 1)) >> 16;   // round-nearest-even
    return (unsigned short)u;
}

// ---------------- zero cnt ----------------
__global__ void zero_k(int* __restrict__ p, int n) {
    int i = blockIdx.x * 256 + threadIdx.x;
    if (i < n) p[i] = 0;
}

// ---------------- wsh[k][o] = sum_c W[k, o*32+c] * att[o][c], o in [0,16) ----------------
__global__ void precompute_k(const float* __restrict__ W,
                             const float* __restrict__ att_s,
                             const float* __restrict__ att_d,
                             float* __restrict__ wsh) {
    int idx = blockIdx.x * 256 + threadIdx.x;
    if (idx >= F_IN * 16) return;
    int k = idx >> 4, o = idx & 15;
    const float* a = (o < 8) ? (att_s + o * 32) : (att_d + (o - 8) * 32);
    const float* Wp = W + k * HC + (o & 7) * 32;
    float s = 0.f;
#pragma unroll
    for (int c = 0; c < 32; ++c) s = fmaf(Wp[c], a[c], s);
    wsh[idx] = s;
}

// ---------------- GEMM: xth[N,256](bf16) = bf16(x[N,116] @ W[116,256]) ----------------
// 512 threads = 8 waves; block covers 64 rows, wave w rows [w*8, w*8+8).
__global__ __launch_bounds__(512) void gemm_xt(const float* __restrict__ x,
                                               const float* __restrict__ W,
                                               unsigned short* __restrict__ xth, int N) {
    __shared__ float xs[64 * F_IN];           // 29696 B
    const int t = threadIdx.x;
    const int row0 = blockIdx.x * 64;
    const int nrows = (N - row0 < 64) ? (N - row0) : 64;
    const int tot = nrows * F_IN;
    for (int i = t; i < tot; i += 512) xs[i] = x[(size_t)row0 * F_IN + i];
    __syncthreads();

    const int w = t >> 6;
    const int lane = t & 63;
    const int r0 = w * 8;

    float acc[8][4];
#pragma unroll
    for (int r = 0; r < 8; ++r)
#pragma unroll
        for (int j = 0; j < 4; ++j) acc[r][j] = 0.f;

    for (int k4 = 0; k4 < F_IN / 4; ++k4) {
        const int k = k4 * 4;
        float w0[4], w1[4], w2[4], w3[4];
#pragma unroll
        for (int j = 0; j < 4; ++j) {
            const float* Wk = W + k * HC + lane + 64 * j;
            w0[j] = Wk[0];
            w1[j] = Wk[HC];
            w2[j] = Wk[2 * HC];
            w3[j] = Wk[3 * HC];
        }
#pragma unroll
        for (int r = 0; r < 8; ++r) {
            float4 xv = *(const float4*)&xs[(r0 + r) * F_IN + k];
#pragma unroll
            for (int j = 0; j < 4; ++j)
                acc[r][j] = fmaf(xv.x, w0[j],
                            fmaf(xv.y, w1[j],
                            fmaf(xv.z, w2[j],
                            fmaf(xv.w, w3[j], acc[r][j]))));
        }
    }

#pragma unroll
    for (int r = 0; r < 8; ++r) {
        const int row = row0 + r0 + r;
        if (row < N) {
#pragma unroll
            for (int j = 0; j < 4; ++j)
                xth[(size_t)row * HC + lane + 64 * j] = f2bf(acc[r][j]);
        }
    }
}

// ---------------- alphas: [asrc|adst][n, 0..16) = x[n,:] @ wsh ----------------
// 4 waves/block, one row per wave. Lane l: output o=l&15, k-part l>>4 (4x29).
__global__ __launch_bounds__(256) void alphas_k(const float* __restrict__ x,
                                                const float* __restrict__ wsh,
                                                float* __restrict__ asrc,
                                                float* __restrict__ adst, int N) {
    __shared__ float ws[F_IN * 16];
    const int t = threadIdx.x;
    for (int i = t; i < F_IN * 16; i += 256) ws[i] = wsh[i];
    __syncthreads();

    const int row = blockIdx.x * 4 + (t >> 6);
    if (row >= N) return;
    const int l = t & 63;
    const int o = l & 15;
    const int part = l >> 4;                 // 4 parts x 29 k
    const float* xr = x + (size_t)row * F_IN + part * 29;
    float s = 0.f;
#pragma unroll
    for (int i = 0; i < 29; ++i) s = fmaf(xr[i], ws[(part * 29 + i) * 16 + o], s);
    s += __shfl_xor(s, 16, 64);
    s += __shfl_xor(s, 32, 64);
    if (l < 16) {
        if (o < 8) asrc[row * NHEAD + o] = s;
        else       adst[row * NHEAD + o - 8] = s;
    }
}

// ---------------- in-degree histogram + per-edge rank ----------------
__global__ void hist_k(const int* __restrict__ dst, int* __restrict__ cnt,
                       int* __restrict__ rank, int E) {
    int e = blockIdx.x * 256 + threadIdx.x;
    if (e < E) rank[e] = atomicAdd(&cnt[dst[e]], 1);
}

// ---------------- scan over N+1 elems (local prefix + block sums) ----------------
__global__ __launch_bounds__(256) void scan1_k(const int* __restrict__ cnt,
                                               int* __restrict__ offs,
                                               int* __restrict__ bsum, int N) {
    __shared__ int ts[256];
    const int t = threadIdx.x;
    const int base = blockIdx.x * 1024 + t * 4;
    int v[4];
    int s = 0;
#pragma unroll
    for (int j = 0; j < 4; ++j) {
        v[j] = (base + j < N) ? cnt[base + j] : 0;
        s += v[j];
    }
    ts[t] = s;
    __syncthreads();
    for (int off = 1; off < 256; off <<= 1) {
        int u = (t >= off) ? ts[t - off] : 0;
        __syncthreads();
        ts[t] += u;
        __syncthreads();
    }
    int run = t ? ts[t - 1] : 0;
#pragma unroll
    for (int j = 0; j < 4; ++j) {
        if (base + j <= N) offs[base + j] = run;   // include offs[N]
        run += v[j];
    }
    if (t == 255) bsum[blockIdx.x] = ts[255];
}

__global__ void scan2_k(int* __restrict__ bsum, int nb) {
    if (threadIdx.x == 0 && blockIdx.x == 0) {
        int run = 0;
        for (int b = 0; b < nb; ++b) {
            int v = bsum[b];
            bsum[b] = run;
            run += v;
        }
    }
}

// ---------------- CSR scatter, no atomics ----------------
__global__ void scatter_k(const int* __restrict__ src, const int* __restrict__ dst,
                          const int* __restrict__ rank,
                          const int* __restrict__ offs, const int* __restrict__ bsum,
                          int* __restrict__ csr, int E) {
    int e = blockIdx.x * 256 + threadIdx.x;
    if (e >= E) return;
    int d = dst[e];
    int p = offs[d] + bsum[d >> 10] + rank[e];
    csr[p] = src[e];
}

// ---------------- aggregate: one WAVE per destination node ----------------
// Lane l: fma-head h_f = l>>3, channels [4l, 4l+4). Weight-compute mapping:
// chunk-local edge l>>3, head l&7.
__global__ __launch_bounds__(256) void aggregate_k(const unsigned short* __restrict__ xth,
                                                   const float* __restrict__ asrc,
                                                   const float* __restrict__ adst,
                                                   const int* __restrict__ offs,
                                                   const int* __restrict__ bsum,
                                                   const int* __restrict__ csr,
                                                   const float* __restrict__ bias,
                                                   float* __restrict__ out, int N) {
    const int t = threadIdx.x;
    const int l = t & 63;
    const int n = blockIdx.x * 4 + (t >> 6);
    if (n >= N) return;

    const int h_f = l >> 3;          // head for fma/accumulation
    const int h_w = l & 7;           // head for weight compute
    const int e_w = l >> 3;          // chunk-local edge for weight compute

    const int beg = offs[n] + bsum[n >> 10];
    const int d = offs[n + 1] + bsum[(n + 1) >> 10] - beg;

    const float adst_hw = adst[n * NHEAD + h_w];

    // self-loop
    float zs = asrc[n * NHEAD + h_f] + adst[n * NHEAD + h_f];
    zs = (zs > 0.f) ? zs : 0.2f * zs;
    const float wself = __expf(zs);

    uint2 sv = ((const uint2*)(xth + (size_t)n * HC))[l];
    float a0 = wself * __uint_as_float(sv.x << 16);
    float a1 = wself * __uint_as_float(sv.x & 0xFFFF0000u);
    float a2 = wself * __uint_as_float(sv.y << 16);
    float a3 = wself * __uint_as_float(sv.y & 0xFFFF0000u);
    float wsum = wself;

    const int nfull = d >> 3;
    const int rem = d & 7;
    int pos = beg;
    for (int cch = 0; cch < nfull; ++cch, pos += 8) {
        int s_w = csr[pos + e_w];
        float z = asrc[s_w * NHEAD + h_w] + adst_hw;
        z = (z > 0.f) ? z : 0.2f * z;
        float w_reg = __expf(z);
#pragma unroll
        for (int e = 0; e < 8; ++e) {
            int s = __shfl(s_w, e << 3, 64);
            float w = __shfl(w_reg, (e << 3) + h_f, 64);
            uint2 v = ((const uint2*)(xth + (size_t)s * HC))[l];
            a0 = fmaf(w, __uint_as_float(v.x << 16), a0);
            a1 = fmaf(w, __uint_as_float(v.x & 0xFFFF0000u), a1);
            a2 = fmaf(w, __uint_as_float(v.y << 16), a2);
            a3 = fmaf(w, __uint_as_float(v.y & 0xFFFF0000u), a3);
            wsum += w;
        }
    }
    if (rem) {
        int s_w = (e_w < rem) ? csr[pos + e_w] : n;
        float z = asrc[s_w * NHEAD + h_w] + adst_hw;
        z = (z > 0.f) ? z : 0.2f * z;
        float w_reg = __expf(z);
        for (int e = 0; e < rem; ++e) {
            int s = __shfl(s_w, e << 3, 64);
            float w = __shfl(w_reg, (e << 3) + h_f, 64);
            uint2 v = ((const uint2*)(xth + (size_t)s * HC))[l];
            a0 = fmaf(w, __uint_as_float(v.x << 16), a0);
            a1 = fmaf(w, __uint_as_float(v.x & 0xFFFF0000u), a1);
            a2 = fmaf(w, __uint_as_float(v.y << 16), a2);
            a3 = fmaf(w, __uint_as_float(v.y & 0xFFFF0000u), a3);
            wsum += w;
        }
    }

    const float inv = 1.f / (wsum + 1e-16f);
    a0 *= inv; a1 *= inv; a2 *= inv; a3 *= inv;

    // reduce over heads: lanes with equal (l&7) hold same channel group
#pragma unroll
    for (int o = 8; o <= 32; o <<= 1) {
        a0 += __shfl_xor(a0, o, 64);
        a1 += __shfl_xor(a1, o, 64);
        a2 += __shfl_xor(a2, o, 64);
        a3 += __shfl_xor(a3, o, 64);
    }

    if (l < 8) {
        const float* bp = bias + 4 * l;
        float4 r;
        r.x = fmaxf(a0 * 0.125f + bp[0], 0.f);
        r.y = fmaxf(a1 * 0.125f + bp[1], 0.f);
        r.z = fmaxf(a2 * 0.125f + bp[2], 0.f);
        r.w = fmaxf(a3 * 0.125f + bp[3], 0.f);
        *(float4*)&out[(size_t)n * CDIM + 4 * l] = r;
    }
}

extern "C" void kernel_launch(void* const* d_in, const int* in_sizes, int n_in,
                              void* d_out, int out_size, void* d_ws, size_t ws_size,
                              hipStream_t stream) {
    const float* x     = (const float*)d_in[0];
    const int*   ei    = (const int*)d_in[1];      // [2,E] int32: row0=src, row1=dst
    const float* W     = (const float*)d_in[2];
    const float* att_s = (const float*)d_in[3];
    const float* att_d = (const float*)d_in[4];
    const float* bias  = (const float*)d_in[5];
    float* out = (float*)d_out;

    const int N = in_sizes[0] / F_IN;    // 50000
    const int E = in_sizes[1] / 2;       // 800000

    // workspace layout (16B-aligned slices; N%4==0)
    unsigned short* xth = (unsigned short*)d_ws;          // 256N bf16
    float* asrc = (float*)(xth + (size_t)N * HC);         // 8N f32
    float* adst = asrc + (size_t)N * NHEAD;               // 8N
    float* wsh  = adst + (size_t)N * NHEAD;               // 116*16
    int*   offs = (int*)(wsh + F_IN * 16);                // N+8
    int*   bsum = offs + (N + 8);                         // 64
    int*   cnt  = bsum + 64;                              // N
    int*   rank = cnt + N;                                // E
    int*   csr  = rank + E;                               // E

    const int nb = (N + 1 + 1023) / 1024;

    zero_k<<<(N + 255) / 256, 256, 0, stream>>>(cnt, N);
    precompute_k<<<(F_IN * 16 + 255) / 256, 256, 0, stream>>>(W, att_s, att_d, wsh);
    gemm_xt<<<(N + 63) / 64, 512, 0, stream>>>(x, W, xth, N);
    alphas_k<<<(N + 3) / 4, 256, 0, stream>>>(x, wsh, asrc, adst, N);
    hist_k<<<(E + 255) / 256, 256, 0, stream>>>(ei + E, cnt, rank, E);
    scan1_k<<<nb, 256, 0, stream>>>(cnt, offs, bsum, N);
    scan2_k<<<1, 64, 0, stream>>>(bsum, nb);
    scatter_k<<<(E + 255) / 256, 256, 0, stream>>>(ei, ei + E, rank, offs, bsum, csr, E);
    aggregate_k<<<(N + 3) / 4, 256, 0, stream>>>(xth, asrc, adst, offs, bsum, csr, bias, out, N);
}